// Round 5
// baseline (6211.757 us; speedup 1.0000x reference)
//
#include <hip/hip_runtime.h>

// RVQ v5: rh-only bf16 GEMM (K=256), direct-global A-frags (no LDS staging),
// 512-thr/8-wave blocks, BR=32, 4 blocks/CU target, exact-margin rescue.
// x: [16,4096,256] f32 ; emb: [8,1024,256] f32
// out: [quantized 16777216][loss 1][indices-as-float 524288]
// ws:  [packE 4MB bf16][e2 8192 f32][lossPart 2048 f32]

#define NROWS 65536
#define DDIM  256
#define KC    1024
#define QST   8
#define BR    32
#define MCAP  12

typedef __attribute__((ext_vector_type(8))) short short8;
typedef __attribute__((ext_vector_type(4))) float f32x4;
typedef unsigned int u32;
typedef unsigned short u16;

__device__ __forceinline__ u16 f2bf(float f) {
  u32 b = __float_as_uint(f);
  return (u16)((b + 0x7FFFu + ((b >> 16) & 1u)) >> 16);
}
// byte offset of 16B unit u (0..31) of row's rh, XOR-swizzled (rows are 512B)
__device__ __forceinline__ u32 runit(int row, int u) {
  return (u32)(row * 512 + ((u ^ (row & 7)) << 4));
}

__global__ void e2_kernel(const float* __restrict__ emb, float* __restrict__ e2) {
  const int row  = blockIdx.x * 4 + (threadIdx.x >> 6);
  const int lane = threadIdx.x & 63;
  const float4 v = ((const float4*)(emb + (size_t)row * DDIM))[lane];
  float s = v.x * v.x + v.y * v.y + v.z * v.z + v.w * v.w;
  #pragma unroll
  for (int m = 32; m >= 1; m >>= 1) s += __shfl_xor(s, m);
  if (lane == 0) e2[row] = s;
}

// Pack eh into A-frag stream: slot t=((qi*16+W)*32+c)*64+l, c=(ekt*4+ci):
//   code = 64W+16ci+(l&15), k = 32ekt+8*(l>>4)+j  (8 bf16 per slot)
__global__ void pack_kernel(const float* __restrict__ emb, u16* __restrict__ packE) {
  const int t  = blockIdx.x * 256 + threadIdx.x;   // 262144 slots
  const int l  = t & 63;
  const int c  = (t >> 6) & 31;
  const int W  = (t >> 11) & 15;
  const int qi = t >> 15;
  const int code = 64 * W + 16 * (c & 3) + (l & 15);
  const int k    = 32 * (c >> 2) + 8 * (l >> 4);
  const float* src = emb + ((size_t)qi * KC + code) * DDIM + k;
  short8 v;
  #pragma unroll
  for (int j = 0; j < 8; ++j) v[j] = (short)f2bf(src[j]);
  *(short8*)(packE + (size_t)t * 8) = v;
}

__global__ __launch_bounds__(512, 8)
void rvq_kernel(const float* __restrict__ x, const float* __restrict__ emb,
                const char* __restrict__ packEb, const float* __restrict__ e2g,
                float* __restrict__ out, float* __restrict__ outIdx,
                float* __restrict__ lossPart)
{
  __shared__ __align__(16) u16 Rh[BR * 256];   // 16KB rh residual (swizzled)
  __shared__ float e2L[KC];                    // 4KB
  __shared__ float sredV[8][BR];               // 1KB
  __shared__ int   sredI[8][BR];               // 1KB
  __shared__ float d0L[BR];
  __shared__ int   cntL[BR];
  __shared__ int   candL[BR][MCAP];            // 1.5KB
  __shared__ int   sidx[BR];
  __shared__ float rnormL[BR];
  __shared__ float red[8];

  const int tid = threadIdx.x;
  const int w = tid >> 6, l = tid & 63;
  const int g = l >> 4, rb16 = l & 15;
  const int row = tid >> 4, sub = tid & 15;    // 32 rows x 16 threads
  const size_t rowBase = (size_t)blockIdx.x * BR;
  char* RhB = (char*)Rh;
  float lossAcc = 0.f;
  float r[16];                                 // f32 residual, d = 16*sub + i

  // ---- init: r = x slice; write rh to LDS; rnorm ----
  {
    const float* xp = x + (rowBase + row) * DDIM + 16 * sub;
    float rn = 0.f;
    #pragma unroll
    for (int f = 0; f < 4; ++f) {
      f32x4 v = *(const f32x4*)(xp + 4 * f);
      r[4*f+0] = v.x; r[4*f+1] = v.y; r[4*f+2] = v.z; r[4*f+3] = v.w;
      rn += v.x*v.x + v.y*v.y + v.z*v.z + v.w*v.w;
    }
    short8 h0, h1;
    #pragma unroll
    for (int j = 0; j < 8; ++j) { h0[j] = (short)f2bf(r[j]); h1[j] = (short)f2bf(r[8+j]); }
    *(short8*)(RhB + runit(row, 2*sub))     = h0;
    *(short8*)(RhB + runit(row, 2*sub + 1)) = h1;
    rn += __shfl_xor(rn, 1); rn += __shfl_xor(rn, 2);
    rn += __shfl_xor(rn, 4); rn += __shfl_xor(rn, 8);
    if (sub == 0) rnormL[row] = rn;
  }
  __syncthreads();

  for (int qi = 0; qi < QST; ++qi) {
    e2L[tid]       = e2g[qi * KC + tid];
    e2L[tid + 512] = e2g[qi * KC + 512 + tid];

    // ---- GEMM: wave w covers codes [128w,128w+128) x 32 rows, K=256 ----
    f32x4 acc[8][2];
    #pragma unroll
    for (int a = 0; a < 8; ++a) {
      acc[a][0] = (f32x4){0.f, 0.f, 0.f, 0.f};
      acc[a][1] = (f32x4){0.f, 0.f, 0.f, 0.f};
    }
    const char* src = packEb + ((size_t)(qi * 16 + 2 * w) << 15) + (size_t)l * 16;
    #pragma unroll
    for (int ekt = 0; ekt < 8; ++ekt) {
      short8 Bf0 = *(const short8*)(RhB + runit(rb16,      ekt * 4 + g));
      short8 Bf1 = *(const short8*)(RhB + runit(16 + rb16, ekt * 4 + g));
      #pragma unroll
      for (int ci8 = 0; ci8 < 8; ++ci8) {
        const short8 Af = *(const short8*)(src + ((ci8 >> 2) << 15)
                                               + ((ekt * 4 + (ci8 & 3)) << 10));
        acc[ci8][0] = __builtin_amdgcn_mfma_f32_16x16x32_bf16(Af, Bf0, acc[ci8][0], 0, 0, 0);
        acc[ci8][1] = __builtin_amdgcn_mfma_f32_16x16x32_bf16(Af, Bf1, acc[ci8][1], 0, 0, 0);
      }
    }
    __syncthreads();   // e2L visible; all waves done reading Rh

    // ---- scoring + wave-local argmin ----
    float bestV[2]; int bestI[2];
    bestV[0] = 3.4e38f; bestV[1] = 3.4e38f; bestI[0] = 0; bestI[1] = 0;
    #pragma unroll
    for (int ci8 = 0; ci8 < 8; ++ci8) {
      const int cb = 128 * w + 64 * (ci8 >> 2) + 16 * (ci8 & 3) + 4 * g;
      f32x4 e4 = *(const f32x4*)&e2L[cb];
      #pragma unroll
      for (int jj = 0; jj < 4; ++jj) {
        #pragma unroll
        for (int ri = 0; ri < 2; ++ri) {
          float d = e4[jj] - 2.f * acc[ci8][ri][jj];
          if (d < bestV[ri]) { bestV[ri] = d; bestI[ri] = cb + jj; }
        }
      }
    }
    #pragma unroll
    for (int m = 16; m <= 32; m <<= 1) {
      #pragma unroll
      for (int ri = 0; ri < 2; ++ri) {
        float ov = __shfl_xor(bestV[ri], m);
        int   oi = __shfl_xor(bestI[ri], m);
        if (ov < bestV[ri] || (ov == bestV[ri] && oi < bestI[ri])) { bestV[ri] = ov; bestI[ri] = oi; }
      }
    }
    if (l < 16) {
      sredV[w][l]      = bestV[0]; sredI[w][l]      = bestI[0];
      sredV[w][16 + l] = bestV[1]; sredI[w][16 + l] = bestI[1];
    }
    __syncthreads();

    // ---- cross-wave min (parallel: 8 lanes per row), init counters ----
    if (tid < 256) {
      const int rr = tid >> 3, wv = tid & 7;
      float v = sredV[wv][rr]; int ii = sredI[wv][rr];
      #pragma unroll
      for (int m = 1; m <= 4; m <<= 1) {
        float ov = __shfl_xor(v, m);
        int   oi = __shfl_xor(ii, m);
        if (ov < v || (ov == v && oi < ii)) { v = ov; ii = oi; }
      }
      if (wv == 0) { d0L[rr] = v; sidx[rr] = ii; cntL[rr] = 0; }
    }
    __syncthreads();

    // ---- candidates within guaranteed margin ----
    {
      float thr[2];
      thr[0] = d0L[rb16]      + 0.36f * sqrtf(rnormL[rb16])      + 0.05f;
      thr[1] = d0L[16 + rb16] + 0.36f * sqrtf(rnormL[16 + rb16]) + 0.05f;
      #pragma unroll
      for (int ci8 = 0; ci8 < 8; ++ci8) {
        const int cb = 128 * w + 64 * (ci8 >> 2) + 16 * (ci8 & 3) + 4 * g;
        f32x4 e4 = *(const f32x4*)&e2L[cb];
        #pragma unroll
        for (int jj = 0; jj < 4; ++jj) {
          #pragma unroll
          for (int ri = 0; ri < 2; ++ri) {
            float d = e4[jj] - 2.f * acc[ci8][ri][jj];
            if (d <= thr[ri]) {
              const int rw = 16 * ri + rb16;
              int p = atomicAdd(&cntL[rw], 1);
              if (p < MCAP) candL[rw][p] = cb + jj;
            }
          }
        }
      }
    }
    __syncthreads();

    // ---- exact f32 rescue for contested rows (16 thr/row) ----
    {
      int cnt = cntL[row];
      if (cnt > 1) {
        float bd = 3.4e38f; int bi = 0x7fffffff;
        const int n = (cnt <= MCAP) ? cnt : KC;    // overflow -> full exact scan
        for (int k2 = 0; k2 < n; ++k2) {
          const int c = (cnt <= MCAP) ? candL[row][k2] : k2;
          const float* ep = emb + ((size_t)qi * KC + c) * DDIM + 16 * sub;
          float dot = 0.f;
          #pragma unroll
          for (int f = 0; f < 4; ++f) {
            f32x4 ev = *(const f32x4*)(ep + 4 * f);
            dot += r[4*f+0]*ev.x + r[4*f+1]*ev.y + r[4*f+2]*ev.z + r[4*f+3]*ev.w;
          }
          dot += __shfl_xor(dot, 1); dot += __shfl_xor(dot, 2);
          dot += __shfl_xor(dot, 4); dot += __shfl_xor(dot, 8);
          float d = e2L[c] - 2.f * dot;
          if (d < bd || (d == bd && c < bi)) { bd = d; bi = c; }
        }
        if (sub == 0) sidx[row] = bi;
      }
    }
    __syncthreads();

    // ---- residual update (f32 regs), rewrite rh, loss, rnorm, indices ----
    {
      const int c = sidx[row];
      const float* ep = emb + ((size_t)qi * KC + c) * DDIM + 16 * sub;
      float ls = 0.f;
      #pragma unroll
      for (int f = 0; f < 4; ++f) {
        f32x4 ev = *(const f32x4*)(ep + 4 * f);
        r[4*f+0] -= ev.x; ls += r[4*f+0]*r[4*f+0];
        r[4*f+1] -= ev.y; ls += r[4*f+1]*r[4*f+1];
        r[4*f+2] -= ev.z; ls += r[4*f+2]*r[4*f+2];
        r[4*f+3] -= ev.w; ls += r[4*f+3]*r[4*f+3];
      }
      short8 h0, h1;
      #pragma unroll
      for (int j = 0; j < 8; ++j) { h0[j] = (short)f2bf(r[j]); h1[j] = (short)f2bf(r[8+j]); }
      *(short8*)(RhB + runit(row, 2*sub))     = h0;
      *(short8*)(RhB + runit(row, 2*sub + 1)) = h1;
      lossAcc += ls;
      float rn = ls;
      rn += __shfl_xor(rn, 1); rn += __shfl_xor(rn, 2);
      rn += __shfl_xor(rn, 4); rn += __shfl_xor(rn, 8);
      if (sub == 0) rnormL[row] = rn;
      if (tid < BR) outIdx[(rowBase + tid) * QST + qi] = (float)sidx[tid];
    }
    __syncthreads();
  }

  // ---- final: out = x - r_final ----
  {
    const float* xp = x + (rowBase + row) * DDIM + 16 * sub;
    float* op = out + (rowBase + row) * DDIM + 16 * sub;
    #pragma unroll
    for (int f = 0; f < 4; ++f) {
      f32x4 xv = *(const f32x4*)(xp + 4 * f);
      f32x4 o;
      o.x = xv.x - r[4*f+0]; o.y = xv.y - r[4*f+1];
      o.z = xv.z - r[4*f+2]; o.w = xv.w - r[4*f+3];
      *(f32x4*)(op + 4 * f) = o;
    }
  }

  // ---- deterministic per-block loss partial ----
  {
    float s = lossAcc;
    #pragma unroll
    for (int m = 32; m >= 1; m >>= 1) s += __shfl_xor(s, m);
    if (l == 0) red[w] = s;
    __syncthreads();
    if (tid == 0) {
      float t2 = 0.f;
      #pragma unroll
      for (int wv = 0; wv < 8; ++wv) t2 += red[wv];
      lossPart[blockIdx.x] = t2;
    }
  }
}

__global__ void loss_final(const float* __restrict__ part, float* __restrict__ outLoss) {
  __shared__ float buf[256];
  const int t = threadIdx.x;
  float s = 0.f;
  #pragma unroll
  for (int k = 0; k < 8; ++k) s += part[t + 256 * k];
  buf[t] = s;
  __syncthreads();
  for (int st = 128; st >= 1; st >>= 1) {
    if (t < st) buf[t] += buf[t + st];
    __syncthreads();
  }
  if (t == 0) *outLoss = buf[0] * (1.25f / 16777216.f);
}

extern "C" void kernel_launch(void* const* d_in, const int* in_sizes, int n_in,
                              void* d_out, int out_size, void* d_ws, size_t ws_size,
                              hipStream_t stream) {
  (void)in_sizes; (void)n_in; (void)out_size; (void)ws_size;
  const float* x   = (const float*)d_in[0];
  const float* emb = (const float*)d_in[1];
  float* out     = (float*)d_out;
  float* outLoss = out + (size_t)NROWS * DDIM;            // 16777216
  float* outIdx  = outLoss + 1;                           // indices as float
  char*  packE   = (char*)d_ws;                           // 4 MB bf16 A-frag stream
  float* e2      = (float*)(packE + (size_t)QST * 16 * 32 * 1024);  // 8192 f32
  float* part    = e2 + QST * KC;                         // 2048 f32

  pack_kernel<<<dim3(1024), dim3(256), 0, stream>>>(emb, (u16*)packE);
  e2_kernel<<<dim3(QST * KC / 4), dim3(256), 0, stream>>>(emb, e2);
  rvq_kernel<<<dim3(NROWS / BR), dim3(512), 0, stream>>>(x, emb, packE, e2, out, outIdx, part);
  loss_final<<<dim3(1), dim3(256), 0, stream>>>(part, outLoss);
}

// Round 6
// 1490.150 us; speedup vs baseline: 4.1685x; 4.1685x over previous
//
#include <hip/hip_runtime.h>

// RVQ v6: rh-only bf16 GEMM (K=256), direct-global A-frags, 512thr/(512,4)
// -> 128 VGPR cap, 2 blocks/CU. Index-free argmin (index via candidate list),
// e2 preloaded for all stages, exact-margin rescue.
// x: [16,4096,256] f32 ; emb: [8,1024,256] f32
// out: [quantized 16777216][loss 1][indices-as-float 524288]
// ws:  [packE 4MB bf16][e2 8192 f32][lossPart 2048 f32]

#define NROWS 65536
#define DDIM  256
#define KC    1024
#define QST   8
#define BR    32
#define MCAP  12

typedef __attribute__((ext_vector_type(8))) short short8;
typedef __attribute__((ext_vector_type(4))) float f32x4;
typedef unsigned int u32;
typedef unsigned short u16;

__device__ __forceinline__ u16 f2bf(float f) {
  u32 b = __float_as_uint(f);
  return (u16)((b + 0x7FFFu + ((b >> 16) & 1u)) >> 16);
}
// pack 2 f32 -> 2 bf16 (RNE), D[15:0]=cvt(lo), D[31:16]=cvt(hi)
__device__ __forceinline__ u32 cvt_pk_bf16(float lo, float hi) {
  u32 d;
  asm("v_cvt_pk_bf16_f32 %0, %1, %2" : "=v"(d) : "v"(lo), "v"(hi));
  return d;
}
// byte offset of 16B unit u (0..31) of row's rh, XOR-swizzled (rows are 512B)
__device__ __forceinline__ u32 runit(int row, int u) {
  return (u32)(row * 512 + ((u ^ (row & 7)) << 4));
}

__global__ void e2_kernel(const float* __restrict__ emb, float* __restrict__ e2) {
  const int row  = blockIdx.x * 4 + (threadIdx.x >> 6);
  const int lane = threadIdx.x & 63;
  const float4 v = ((const float4*)(emb + (size_t)row * DDIM))[lane];
  float s = v.x * v.x + v.y * v.y + v.z * v.z + v.w * v.w;
  #pragma unroll
  for (int m = 32; m >= 1; m >>= 1) s += __shfl_xor(s, m);
  if (lane == 0) e2[row] = s;
}

// Pack eh into A-frag stream: slot t=((qi*16+W)*32+c)*64+l, c=(ekt*4+ci):
//   code = 64W+16ci+(l&15), k = 32ekt+8*(l>>4)+j  (8 bf16 per slot)
__global__ void pack_kernel(const float* __restrict__ emb, u16* __restrict__ packE) {
  const int t  = blockIdx.x * 256 + threadIdx.x;   // 262144 slots
  const int l  = t & 63;
  const int c  = (t >> 6) & 31;
  const int W  = (t >> 11) & 15;
  const int qi = t >> 15;
  const int code = 64 * W + 16 * (c & 3) + (l & 15);
  const int k    = 32 * (c >> 2) + 8 * (l >> 4);
  const float* src = emb + ((size_t)qi * KC + code) * DDIM + k;
  short8 v;
  #pragma unroll
  for (int j = 0; j < 8; ++j) v[j] = (short)f2bf(src[j]);
  *(short8*)(packE + (size_t)t * 8) = v;
}

__global__ __launch_bounds__(512, 4)
void rvq_kernel(const float* __restrict__ x, const float* __restrict__ emb,
                const char* __restrict__ packEb, const float* __restrict__ e2g,
                float* __restrict__ out, float* __restrict__ outIdx,
                float* __restrict__ lossPart)
{
  __shared__ __align__(16) u16  Rh[BR * 256];   // 16KB rh residual (swizzled)
  __shared__ __align__(16) float e2L[QST * KC]; // 32KB all-stage ||e||^2
  __shared__ float sredV[8][BR];                // 1KB
  __shared__ float d0L[BR];
  __shared__ int   cntL[BR];
  __shared__ int   candL[BR][MCAP];             // 1.5KB
  __shared__ int   sidx[BR];
  __shared__ float rnormL[BR];
  __shared__ float red[8];

  const int tid = threadIdx.x;
  const int w = tid >> 6, l = tid & 63;
  const int g = l >> 4, rb16 = l & 15;
  const int row = tid >> 4, sub = tid & 15;     // 32 rows x 16 threads
  const size_t rowBase = (size_t)blockIdx.x * BR;
  char* RhB = (char*)Rh;
  float lossAcc = 0.f;
  float r[16];                                  // f32 residual, d = 16*sub + i

  // ---- preload all e2 (8KB*4) ----
  #pragma unroll
  for (int f = 0; f < 4; ++f)
    *(f32x4*)&e2L[4 * tid + 2048 * f] = *(const f32x4*)&e2g[4 * tid + 2048 * f];

  // ---- init: r = x slice; write rh to LDS; rnorm ----
  {
    const float* xp = x + (rowBase + row) * DDIM + 16 * sub;
    float rn = 0.f;
    #pragma unroll
    for (int f = 0; f < 4; ++f) {
      f32x4 v = *(const f32x4*)(xp + 4 * f);
      r[4*f+0] = v.x; r[4*f+1] = v.y; r[4*f+2] = v.z; r[4*f+3] = v.w;
      rn += v.x*v.x + v.y*v.y + v.z*v.z + v.w*v.w;
    }
    uint4 h0, h1;
    h0.x = cvt_pk_bf16(r[0],  r[1]);  h0.y = cvt_pk_bf16(r[2],  r[3]);
    h0.z = cvt_pk_bf16(r[4],  r[5]);  h0.w = cvt_pk_bf16(r[6],  r[7]);
    h1.x = cvt_pk_bf16(r[8],  r[9]);  h1.y = cvt_pk_bf16(r[10], r[11]);
    h1.z = cvt_pk_bf16(r[12], r[13]); h1.w = cvt_pk_bf16(r[14], r[15]);
    *(uint4*)(RhB + runit(row, 2*sub))     = h0;
    *(uint4*)(RhB + runit(row, 2*sub + 1)) = h1;
    rn += __shfl_xor(rn, 1); rn += __shfl_xor(rn, 2);
    rn += __shfl_xor(rn, 4); rn += __shfl_xor(rn, 8);
    if (sub == 0) rnormL[row] = rn;
  }
  __syncthreads();

  for (int qi = 0; qi < QST; ++qi) {
    const float* e2q = &e2L[qi * KC];

    // ---- GEMM: wave w covers codes [128w,128w+128) x 32 rows, K=256 ----
    f32x4 acc[8][2];
    #pragma unroll
    for (int a = 0; a < 8; ++a) {
      acc[a][0] = (f32x4){0.f, 0.f, 0.f, 0.f};
      acc[a][1] = (f32x4){0.f, 0.f, 0.f, 0.f};
    }
    const char* src = packEb + ((size_t)(qi * 16 + 2 * w) << 15) + (size_t)l * 16;
    #pragma unroll
    for (int ekt = 0; ekt < 8; ++ekt) {
      short8 Bf0 = *(const short8*)(RhB + runit(rb16,      ekt * 4 + g));
      short8 Bf1 = *(const short8*)(RhB + runit(16 + rb16, ekt * 4 + g));
      #pragma unroll
      for (int ci8 = 0; ci8 < 8; ++ci8) {
        const short8 Af = *(const short8*)(src + ((ci8 >> 2) << 15)
                                               + ((ekt * 4 + (ci8 & 3)) << 10));
        acc[ci8][0] = __builtin_amdgcn_mfma_f32_16x16x32_bf16(Af, Bf0, acc[ci8][0], 0, 0, 0);
        acc[ci8][1] = __builtin_amdgcn_mfma_f32_16x16x32_bf16(Af, Bf1, acc[ci8][1], 0, 0, 0);
      }
    }
    __syncthreads();   // all waves done reading Rh

    // ---- scoring: value-only min (no index tracking) ----
    float bv0 = 3.4e38f, bv1 = 3.4e38f;
    #pragma unroll
    for (int ci8 = 0; ci8 < 8; ++ci8) {
      const int cb = 128 * w + 64 * (ci8 >> 2) + 16 * (ci8 & 3) + 4 * g;
      f32x4 e4 = *(const f32x4*)&e2q[cb];
      #pragma unroll
      for (int jj = 0; jj < 4; ++jj) {
        bv0 = fminf(bv0, fmaf(-2.f, acc[ci8][0][jj], e4[jj]));
        bv1 = fminf(bv1, fmaf(-2.f, acc[ci8][1][jj], e4[jj]));
      }
    }
    bv0 = fminf(bv0, __shfl_xor(bv0, 16)); bv0 = fminf(bv0, __shfl_xor(bv0, 32));
    bv1 = fminf(bv1, __shfl_xor(bv1, 16)); bv1 = fminf(bv1, __shfl_xor(bv1, 32));
    if (l < 16) { sredV[w][l] = bv0; sredV[w][16 + l] = bv1; }
    __syncthreads();

    // ---- cross-wave min (8 lanes/row), init counters ----
    if (tid < 256) {
      const int rr = tid >> 3, wv = tid & 7;
      float v = sredV[wv][rr];
      v = fminf(v, __shfl_xor(v, 1));
      v = fminf(v, __shfl_xor(v, 2));
      v = fminf(v, __shfl_xor(v, 4));
      if (wv == 0) { d0L[rr] = v; cntL[rr] = 0; }
    }
    __syncthreads();

    // ---- candidates within guaranteed margin (best code always included) ----
    {
      float thr[2];
      thr[0] = d0L[rb16]      + 0.36f * sqrtf(rnormL[rb16])      + 0.05f;
      thr[1] = d0L[16 + rb16] + 0.36f * sqrtf(rnormL[16 + rb16]) + 0.05f;
      #pragma unroll
      for (int ci8 = 0; ci8 < 8; ++ci8) {
        const int cb = 128 * w + 64 * (ci8 >> 2) + 16 * (ci8 & 3) + 4 * g;
        f32x4 e4 = *(const f32x4*)&e2q[cb];
        #pragma unroll
        for (int jj = 0; jj < 4; ++jj) {
          #pragma unroll
          for (int ri = 0; ri < 2; ++ri) {
            float d = fmaf(-2.f, acc[ci8][ri][jj], e4[jj]);
            if (d <= thr[ri]) {
              const int rw = 16 * ri + rb16;
              int p = atomicAdd(&cntL[rw], 1);
              if (p < MCAP) candL[rw][p] = cb + jj;
            }
          }
        }
      }
    }
    __syncthreads();

    // ---- index resolve: cnt==1 fast path; else exact f32 rescue (16 thr/row) ----
    {
      const int cnt = cntL[row];
      if (cnt == 1) {
        if (sub == 0) sidx[row] = candL[row][0];
      } else {
        float bd = 3.4e38f; int bi = 0x7fffffff;
        const int n = (cnt <= MCAP) ? cnt : KC;    // overflow -> full exact scan
        for (int k2 = 0; k2 < n; ++k2) {
          const int c = (cnt <= MCAP) ? candL[row][k2] : k2;
          const float* ep = emb + ((size_t)qi * KC + c) * DDIM + 16 * sub;
          float dot = 0.f;
          #pragma unroll
          for (int f = 0; f < 4; ++f) {
            f32x4 ev = *(const f32x4*)(ep + 4 * f);
            dot += r[4*f+0]*ev.x + r[4*f+1]*ev.y + r[4*f+2]*ev.z + r[4*f+3]*ev.w;
          }
          dot += __shfl_xor(dot, 1); dot += __shfl_xor(dot, 2);
          dot += __shfl_xor(dot, 4); dot += __shfl_xor(dot, 8);
          float d = e2q[c] - 2.f * dot;
          if (d < bd || (d == bd && c < bi)) { bd = d; bi = c; }
        }
        if (sub == 0) sidx[row] = bi;
      }
    }
    __syncthreads();

    // ---- residual update (f32 regs), rewrite rh, loss, rnorm, indices ----
    {
      const int c = sidx[row];
      const float* ep = emb + ((size_t)qi * KC + c) * DDIM + 16 * sub;
      float ls = 0.f;
      #pragma unroll
      for (int f = 0; f < 4; ++f) {
        f32x4 ev = *(const f32x4*)(ep + 4 * f);
        r[4*f+0] -= ev.x; ls += r[4*f+0]*r[4*f+0];
        r[4*f+1] -= ev.y; ls += r[4*f+1]*r[4*f+1];
        r[4*f+2] -= ev.z; ls += r[4*f+2]*r[4*f+2];
        r[4*f+3] -= ev.w; ls += r[4*f+3]*r[4*f+3];
      }
      uint4 h0, h1;
      h0.x = cvt_pk_bf16(r[0],  r[1]);  h0.y = cvt_pk_bf16(r[2],  r[3]);
      h0.z = cvt_pk_bf16(r[4],  r[5]);  h0.w = cvt_pk_bf16(r[6],  r[7]);
      h1.x = cvt_pk_bf16(r[8],  r[9]);  h1.y = cvt_pk_bf16(r[10], r[11]);
      h1.z = cvt_pk_bf16(r[12], r[13]); h1.w = cvt_pk_bf16(r[14], r[15]);
      *(uint4*)(RhB + runit(row, 2*sub))     = h0;
      *(uint4*)(RhB + runit(row, 2*sub + 1)) = h1;
      lossAcc += ls;
      float rn = ls;
      rn += __shfl_xor(rn, 1); rn += __shfl_xor(rn, 2);
      rn += __shfl_xor(rn, 4); rn += __shfl_xor(rn, 8);
      if (sub == 0) rnormL[row] = rn;
      if (tid < BR) outIdx[(rowBase + tid) * QST + qi] = (float)sidx[tid];
    }
    __syncthreads();
  }

  // ---- final: out = x - r_final ----
  {
    const float* xp = x + (rowBase + row) * DDIM + 16 * sub;
    float* op = out + (rowBase + row) * DDIM + 16 * sub;
    #pragma unroll
    for (int f = 0; f < 4; ++f) {
      f32x4 xv = *(const f32x4*)(xp + 4 * f);
      f32x4 o;
      o.x = xv.x - r[4*f+0]; o.y = xv.y - r[4*f+1];
      o.z = xv.z - r[4*f+2]; o.w = xv.w - r[4*f+3];
      *(f32x4*)(op + 4 * f) = o;
    }
  }

  // ---- deterministic per-block loss partial ----
  {
    float s = lossAcc;
    #pragma unroll
    for (int m = 32; m >= 1; m >>= 1) s += __shfl_xor(s, m);
    if (l == 0) red[w] = s;
    __syncthreads();
    if (tid == 0) {
      float t2 = 0.f;
      #pragma unroll
      for (int wv = 0; wv < 8; ++wv) t2 += red[wv];
      lossPart[blockIdx.x] = t2;
    }
  }
}

__global__ void loss_final(const float* __restrict__ part, float* __restrict__ outLoss) {
  __shared__ float buf[256];
  const int t = threadIdx.x;
  float s = 0.f;
  #pragma unroll
  for (int k = 0; k < 8; ++k) s += part[t + 256 * k];
  buf[t] = s;
  __syncthreads();
  for (int st = 128; st >= 1; st >>= 1) {
    if (t < st) buf[t] += buf[t + st];
    __syncthreads();
  }
  if (t == 0) *outLoss = buf[0] * (1.25f / 16777216.f);
}

extern "C" void kernel_launch(void* const* d_in, const int* in_sizes, int n_in,
                              void* d_out, int out_size, void* d_ws, size_t ws_size,
                              hipStream_t stream) {
  (void)in_sizes; (void)n_in; (void)out_size; (void)ws_size;
  const float* x   = (const float*)d_in[0];
  const float* emb = (const float*)d_in[1];
  float* out     = (float*)d_out;
  float* outLoss = out + (size_t)NROWS * DDIM;            // 16777216
  float* outIdx  = outLoss + 1;                           // indices as float
  char*  packE   = (char*)d_ws;                           // 4 MB bf16 A-frag stream
  float* e2      = (float*)(packE + (size_t)QST * 16 * 32 * 1024);  // 8192 f32
  float* part    = e2 + QST * KC;                         // 2048 f32

  pack_kernel<<<dim3(1024), dim3(256), 0, stream>>>(emb, (u16*)packE);
  e2_kernel<<<dim3(QST * KC / 4), dim3(256), 0, stream>>>(emb, e2);
  rvq_kernel<<<dim3(NROWS / BR), dim3(512), 0, stream>>>(x, emb, packE, e2, out, outIdx, part);
  loss_final<<<dim3(1), dim3(256), 0, stream>>>(part, outLoss);
}

// Round 7
// 1446.781 us; speedup vs baseline: 4.2935x; 1.0300x over previous
//
#include <hip/hip_runtime.h>

// RVQ v7 = v6 with the register-tier fix: __launch_bounds__(512, 2).
// Empirical finding (R5/R6): 2nd launch_bounds arg behaves as CUDA-style
// min-BLOCKS-per-CU on this toolchain -> VGPR cap = 2048/(arg2*8 waves).
// (512,4) gave 64 VGPR + 660MB spill; (512,2) targets the 128-VGPR tier.
// x: [16,4096,256] f32 ; emb: [8,1024,256] f32
// out: [quantized 16777216][loss 1][indices-as-float 524288]
// ws:  [packE 4MB bf16][e2 8192 f32][lossPart 2048 f32]

#define NROWS 65536
#define DDIM  256
#define KC    1024
#define QST   8
#define BR    32
#define MCAP  12

typedef __attribute__((ext_vector_type(8))) short short8;
typedef __attribute__((ext_vector_type(4))) float f32x4;
typedef unsigned int u32;
typedef unsigned short u16;

__device__ __forceinline__ u16 f2bf(float f) {
  u32 b = __float_as_uint(f);
  return (u16)((b + 0x7FFFu + ((b >> 16) & 1u)) >> 16);
}
// pack 2 f32 -> 2 bf16 (RNE), D[15:0]=cvt(lo), D[31:16]=cvt(hi)
__device__ __forceinline__ u32 cvt_pk_bf16(float lo, float hi) {
  u32 d;
  asm("v_cvt_pk_bf16_f32 %0, %1, %2" : "=v"(d) : "v"(lo), "v"(hi));
  return d;
}
// byte offset of 16B unit u (0..31) of row's rh, XOR-swizzled (rows are 512B)
__device__ __forceinline__ u32 runit(int row, int u) {
  return (u32)(row * 512 + ((u ^ (row & 7)) << 4));
}

__global__ void e2_kernel(const float* __restrict__ emb, float* __restrict__ e2) {
  const int row  = blockIdx.x * 4 + (threadIdx.x >> 6);
  const int lane = threadIdx.x & 63;
  const float4 v = ((const float4*)(emb + (size_t)row * DDIM))[lane];
  float s = v.x * v.x + v.y * v.y + v.z * v.z + v.w * v.w;
  #pragma unroll
  for (int m = 32; m >= 1; m >>= 1) s += __shfl_xor(s, m);
  if (lane == 0) e2[row] = s;
}

// Pack eh into A-frag stream: slot t=((qi*16+W)*32+c)*64+l, c=(ekt*4+ci):
//   code = 64W+16ci+(l&15), k = 32ekt+8*(l>>4)+j  (8 bf16 per slot)
__global__ void pack_kernel(const float* __restrict__ emb, u16* __restrict__ packE) {
  const int t  = blockIdx.x * 256 + threadIdx.x;   // 262144 slots
  const int l  = t & 63;
  const int c  = (t >> 6) & 31;
  const int W  = (t >> 11) & 15;
  const int qi = t >> 15;
  const int code = 64 * W + 16 * (c & 3) + (l & 15);
  const int k    = 32 * (c >> 2) + 8 * (l >> 4);
  const float* src = emb + ((size_t)qi * KC + code) * DDIM + k;
  short8 v;
  #pragma unroll
  for (int j = 0; j < 8; ++j) v[j] = (short)f2bf(src[j]);
  *(short8*)(packE + (size_t)t * 8) = v;
}

__global__ __launch_bounds__(512, 2)
void rvq_kernel(const float* __restrict__ x, const float* __restrict__ emb,
                const char* __restrict__ packEb, const float* __restrict__ e2g,
                float* __restrict__ out, float* __restrict__ outIdx,
                float* __restrict__ lossPart)
{
  __shared__ __align__(16) u16  Rh[BR * 256];   // 16KB rh residual (swizzled)
  __shared__ __align__(16) float e2L[QST * KC]; // 32KB all-stage ||e||^2
  __shared__ float sredV[8][BR];                // 1KB
  __shared__ float d0L[BR];
  __shared__ int   cntL[BR];
  __shared__ int   candL[BR][MCAP];             // 1.5KB
  __shared__ int   sidx[BR];
  __shared__ float rnormL[BR];
  __shared__ float red[8];

  const int tid = threadIdx.x;
  const int w = tid >> 6, l = tid & 63;
  const int g = l >> 4, rb16 = l & 15;
  const int row = tid >> 4, sub = tid & 15;     // 32 rows x 16 threads
  const size_t rowBase = (size_t)blockIdx.x * BR;
  char* RhB = (char*)Rh;
  float lossAcc = 0.f;
  float r[16];                                  // f32 residual, d = 16*sub + i

  // ---- preload all e2 (8KB*4) ----
  #pragma unroll
  for (int f = 0; f < 4; ++f)
    *(f32x4*)&e2L[4 * tid + 2048 * f] = *(const f32x4*)&e2g[4 * tid + 2048 * f];

  // ---- init: r = x slice; write rh to LDS; rnorm ----
  {
    const float* xp = x + (rowBase + row) * DDIM + 16 * sub;
    float rn = 0.f;
    #pragma unroll
    for (int f = 0; f < 4; ++f) {
      f32x4 v = *(const f32x4*)(xp + 4 * f);
      r[4*f+0] = v.x; r[4*f+1] = v.y; r[4*f+2] = v.z; r[4*f+3] = v.w;
      rn += v.x*v.x + v.y*v.y + v.z*v.z + v.w*v.w;
    }
    uint4 h0, h1;
    h0.x = cvt_pk_bf16(r[0],  r[1]);  h0.y = cvt_pk_bf16(r[2],  r[3]);
    h0.z = cvt_pk_bf16(r[4],  r[5]);  h0.w = cvt_pk_bf16(r[6],  r[7]);
    h1.x = cvt_pk_bf16(r[8],  r[9]);  h1.y = cvt_pk_bf16(r[10], r[11]);
    h1.z = cvt_pk_bf16(r[12], r[13]); h1.w = cvt_pk_bf16(r[14], r[15]);
    *(uint4*)(RhB + runit(row, 2*sub))     = h0;
    *(uint4*)(RhB + runit(row, 2*sub + 1)) = h1;
    rn += __shfl_xor(rn, 1); rn += __shfl_xor(rn, 2);
    rn += __shfl_xor(rn, 4); rn += __shfl_xor(rn, 8);
    if (sub == 0) rnormL[row] = rn;
  }
  __syncthreads();

  for (int qi = 0; qi < QST; ++qi) {
    const float* e2q = &e2L[qi * KC];

    // ---- GEMM: wave w covers codes [128w,128w+128) x 32 rows, K=256 ----
    f32x4 acc[8][2];
    #pragma unroll
    for (int a = 0; a < 8; ++a) {
      acc[a][0] = (f32x4){0.f, 0.f, 0.f, 0.f};
      acc[a][1] = (f32x4){0.f, 0.f, 0.f, 0.f};
    }
    const char* src = packEb + ((size_t)(qi * 16 + 2 * w) << 15) + (size_t)l * 16;
    #pragma unroll
    for (int ekt = 0; ekt < 8; ++ekt) {
      short8 Bf0 = *(const short8*)(RhB + runit(rb16,      ekt * 4 + g));
      short8 Bf1 = *(const short8*)(RhB + runit(16 + rb16, ekt * 4 + g));
      #pragma unroll
      for (int ci8 = 0; ci8 < 8; ++ci8) {
        const short8 Af = *(const short8*)(src + ((ci8 >> 2) << 15)
                                               + ((ekt * 4 + (ci8 & 3)) << 10));
        acc[ci8][0] = __builtin_amdgcn_mfma_f32_16x16x32_bf16(Af, Bf0, acc[ci8][0], 0, 0, 0);
        acc[ci8][1] = __builtin_amdgcn_mfma_f32_16x16x32_bf16(Af, Bf1, acc[ci8][1], 0, 0, 0);
      }
    }
    __syncthreads();   // all waves done reading Rh

    // ---- scoring: value-only min (no index tracking) ----
    float bv0 = 3.4e38f, bv1 = 3.4e38f;
    #pragma unroll
    for (int ci8 = 0; ci8 < 8; ++ci8) {
      const int cb = 128 * w + 64 * (ci8 >> 2) + 16 * (ci8 & 3) + 4 * g;
      f32x4 e4 = *(const f32x4*)&e2q[cb];
      #pragma unroll
      for (int jj = 0; jj < 4; ++jj) {
        bv0 = fminf(bv0, fmaf(-2.f, acc[ci8][0][jj], e4[jj]));
        bv1 = fminf(bv1, fmaf(-2.f, acc[ci8][1][jj], e4[jj]));
      }
    }
    bv0 = fminf(bv0, __shfl_xor(bv0, 16)); bv0 = fminf(bv0, __shfl_xor(bv0, 32));
    bv1 = fminf(bv1, __shfl_xor(bv1, 16)); bv1 = fminf(bv1, __shfl_xor(bv1, 32));
    if (l < 16) { sredV[w][l] = bv0; sredV[w][16 + l] = bv1; }
    __syncthreads();

    // ---- cross-wave min (8 lanes/row), init counters ----
    if (tid < 256) {
      const int rr = tid >> 3, wv = tid & 7;
      float v = sredV[wv][rr];
      v = fminf(v, __shfl_xor(v, 1));
      v = fminf(v, __shfl_xor(v, 2));
      v = fminf(v, __shfl_xor(v, 4));
      if (wv == 0) { d0L[rr] = v; cntL[rr] = 0; }
    }
    __syncthreads();

    // ---- candidates within guaranteed margin (best code always included) ----
    {
      float thr[2];
      thr[0] = d0L[rb16]      + 0.36f * sqrtf(rnormL[rb16])      + 0.05f;
      thr[1] = d0L[16 + rb16] + 0.36f * sqrtf(rnormL[16 + rb16]) + 0.05f;
      #pragma unroll
      for (int ci8 = 0; ci8 < 8; ++ci8) {
        const int cb = 128 * w + 64 * (ci8 >> 2) + 16 * (ci8 & 3) + 4 * g;
        f32x4 e4 = *(const f32x4*)&e2q[cb];
        #pragma unroll
        for (int jj = 0; jj < 4; ++jj) {
          #pragma unroll
          for (int ri = 0; ri < 2; ++ri) {
            float d = fmaf(-2.f, acc[ci8][ri][jj], e4[jj]);
            if (d <= thr[ri]) {
              const int rw = 16 * ri + rb16;
              int p = atomicAdd(&cntL[rw], 1);
              if (p < MCAP) candL[rw][p] = cb + jj;
            }
          }
        }
      }
    }
    __syncthreads();

    // ---- index resolve: cnt==1 fast path; else exact f32 rescue (16 thr/row) ----
    {
      const int cnt = cntL[row];
      if (cnt == 1) {
        if (sub == 0) sidx[row] = candL[row][0];
      } else {
        float bd = 3.4e38f; int bi = 0x7fffffff;
        const int n = (cnt <= MCAP) ? cnt : KC;    // overflow -> full exact scan
        for (int k2 = 0; k2 < n; ++k2) {
          const int c = (cnt <= MCAP) ? candL[row][k2] : k2;
          const float* ep = emb + ((size_t)qi * KC + c) * DDIM + 16 * sub;
          float dot = 0.f;
          #pragma unroll
          for (int f = 0; f < 4; ++f) {
            f32x4 ev = *(const f32x4*)(ep + 4 * f);
            dot += r[4*f+0]*ev.x + r[4*f+1]*ev.y + r[4*f+2]*ev.z + r[4*f+3]*ev.w;
          }
          dot += __shfl_xor(dot, 1); dot += __shfl_xor(dot, 2);
          dot += __shfl_xor(dot, 4); dot += __shfl_xor(dot, 8);
          float d = e2q[c] - 2.f * dot;
          if (d < bd || (d == bd && c < bi)) { bd = d; bi = c; }
        }
        if (sub == 0) sidx[row] = bi;
      }
    }
    __syncthreads();

    // ---- residual update (f32 regs), rewrite rh, loss, rnorm, indices ----
    {
      const int c = sidx[row];
      const float* ep = emb + ((size_t)qi * KC + c) * DDIM + 16 * sub;
      float ls = 0.f;
      #pragma unroll
      for (int f = 0; f < 4; ++f) {
        f32x4 ev = *(const f32x4*)(ep + 4 * f);
        r[4*f+0] -= ev.x; ls += r[4*f+0]*r[4*f+0];
        r[4*f+1] -= ev.y; ls += r[4*f+1]*r[4*f+1];
        r[4*f+2] -= ev.z; ls += r[4*f+2]*r[4*f+2];
        r[4*f+3] -= ev.w; ls += r[4*f+3]*r[4*f+3];
      }
      uint4 h0, h1;
      h0.x = cvt_pk_bf16(r[0],  r[1]);  h0.y = cvt_pk_bf16(r[2],  r[3]);
      h0.z = cvt_pk_bf16(r[4],  r[5]);  h0.w = cvt_pk_bf16(r[6],  r[7]);
      h1.x = cvt_pk_bf16(r[8],  r[9]);  h1.y = cvt_pk_bf16(r[10], r[11]);
      h1.z = cvt_pk_bf16(r[12], r[13]); h1.w = cvt_pk_bf16(r[14], r[15]);
      *(uint4*)(RhB + runit(row, 2*sub))     = h0;
      *(uint4*)(RhB + runit(row, 2*sub + 1)) = h1;
      lossAcc += ls;
      float rn = ls;
      rn += __shfl_xor(rn, 1); rn += __shfl_xor(rn, 2);
      rn += __shfl_xor(rn, 4); rn += __shfl_xor(rn, 8);
      if (sub == 0) rnormL[row] = rn;
      if (tid < BR) outIdx[(rowBase + tid) * QST + qi] = (float)sidx[tid];
    }
    __syncthreads();
  }

  // ---- final: out = x - r_final ----
  {
    const float* xp = x + (rowBase + row) * DDIM + 16 * sub;
    float* op = out + (rowBase + row) * DDIM + 16 * sub;
    #pragma unroll
    for (int f = 0; f < 4; ++f) {
      f32x4 xv = *(const f32x4*)(xp + 4 * f);
      f32x4 o;
      o.x = xv.x - r[4*f+0]; o.y = xv.y - r[4*f+1];
      o.z = xv.z - r[4*f+2]; o.w = xv.w - r[4*f+3];
      *(f32x4*)(op + 4 * f) = o;
    }
  }

  // ---- deterministic per-block loss partial ----
  {
    float s = lossAcc;
    #pragma unroll
    for (int m = 32; m >= 1; m >>= 1) s += __shfl_xor(s, m);
    if (l == 0) red[w] = s;
    __syncthreads();
    if (tid == 0) {
      float t2 = 0.f;
      #pragma unroll
      for (int wv = 0; wv < 8; ++wv) t2 += red[wv];
      lossPart[blockIdx.x] = t2;
    }
  }
}

__global__ void loss_final(const float* __restrict__ part, float* __restrict__ outLoss) {
  __shared__ float buf[256];
  const int t = threadIdx.x;
  float s = 0.f;
  #pragma unroll
  for (int k = 0; k < 8; ++k) s += part[t + 256 * k];
  buf[t] = s;
  __syncthreads();
  for (int st = 128; st >= 1; st >>= 1) {
    if (t < st) buf[t] += buf[t + st];
    __syncthreads();
  }
  if (t == 0) *outLoss = buf[0] * (1.25f / 16777216.f);
}

extern "C" void kernel_launch(void* const* d_in, const int* in_sizes, int n_in,
                              void* d_out, int out_size, void* d_ws, size_t ws_size,
                              hipStream_t stream) {
  (void)in_sizes; (void)n_in; (void)out_size; (void)ws_size;
  const float* x   = (const float*)d_in[0];
  const float* emb = (const float*)d_in[1];
  float* out     = (float*)d_out;
  float* outLoss = out + (size_t)NROWS * DDIM;            // 16777216
  float* outIdx  = outLoss + 1;                           // indices as float
  char*  packE   = (char*)d_ws;                           // 4 MB bf16 A-frag stream
  float* e2      = (float*)(packE + (size_t)QST * 16 * 32 * 1024);  // 8192 f32
  float* part    = e2 + QST * KC;                         // 2048 f32

  pack_kernel<<<dim3(1024), dim3(256), 0, stream>>>(emb, (u16*)packE);
  e2_kernel<<<dim3(QST * KC / 4), dim3(256), 0, stream>>>(emb, e2);
  rvq_kernel<<<dim3(NROWS / BR), dim3(512), 0, stream>>>(x, emb, packE, e2, out, outIdx, part);
  loss_final<<<dim3(1), dim3(256), 0, stream>>>(part, outLoss);
}

// Round 8
// 1247.854 us; speedup vs baseline: 4.9779x; 1.1594x over previous
//
#include <hip/hip_runtime.h>

// RVQ v8: 16-wave/1024-thr blocks (BR=32), per-wave 64-code tile (acc=32 VGPR),
// 3 barriers/stage: packed-u64 LDS atomicMin argmin + fused resolve/rescue/update.
// rh-only bf16 GEMM (K=256) + guaranteed-margin exact rescue (unchanged semantics).
// x: [16,4096,256] f32 ; emb: [8,1024,256] f32
// out: [quantized 16777216][loss 1][indices-as-float 524288]
// ws:  [packE 4MB bf16][e2 8192 f32][lossPart 2048 f32]

#define NROWS 65536
#define DDIM  256
#define KC    1024
#define QST   8
#define BR    32
#define MCAP  12

typedef __attribute__((ext_vector_type(8))) short short8;
typedef __attribute__((ext_vector_type(4))) float f32x4;
typedef unsigned int u32;
typedef unsigned long long u64;
typedef unsigned short u16;

__device__ __forceinline__ u16 f2bf(float f) {
  u32 b = __float_as_uint(f);
  return (u16)((b + 0x7FFFu + ((b >> 16) & 1u)) >> 16);
}
__device__ __forceinline__ u32 cvt_pk_bf16(float lo, float hi) {
  u32 d;
  asm("v_cvt_pk_bf16_f32 %0, %1, %2" : "=v"(d) : "v"(lo), "v"(hi));
  return d;
}
// byte offset of 16B unit u (0..31) of row's rh, XOR-swizzled (rows are 512B)
__device__ __forceinline__ u32 runit(int row, int u) {
  return (u32)(row * 512 + ((u ^ (row & 7)) << 4));
}
// monotone f32 -> u32 key (ascending float order == ascending unsigned order)
__device__ __forceinline__ u32 fkey(float v) {
  u32 b = __float_as_uint(v);
  return b ^ (0x80000000u | (u32)((int)b >> 31));
}
__device__ __forceinline__ u64 pkey(float v, int idx) {
  return ((u64)fkey(v) << 32) | (u32)idx;
}
__device__ __forceinline__ float unfkey(u32 m) {
  u32 b = (m & 0x80000000u) ? (m ^ 0x80000000u) : ~m;
  return __uint_as_float(b);
}

__global__ void e2_kernel(const float* __restrict__ emb, float* __restrict__ e2) {
  const int row  = blockIdx.x * 4 + (threadIdx.x >> 6);
  const int lane = threadIdx.x & 63;
  const float4 v = ((const float4*)(emb + (size_t)row * DDIM))[lane];
  float s = v.x * v.x + v.y * v.y + v.z * v.z + v.w * v.w;
  #pragma unroll
  for (int m = 32; m >= 1; m >>= 1) s += __shfl_xor(s, m);
  if (lane == 0) e2[row] = s;
}

// Pack eh into A-frag stream: slot t=((qi*16+W)*32+c)*64+l, c=(ekt*4+ci):
//   code = 64W+16ci+(l&15), k = 32ekt+8*(l>>4)+j  (8 bf16 per slot)
__global__ void pack_kernel(const float* __restrict__ emb, u16* __restrict__ packE) {
  const int t  = blockIdx.x * 256 + threadIdx.x;   // 262144 slots
  const int l  = t & 63;
  const int c  = (t >> 6) & 31;
  const int W  = (t >> 11) & 15;
  const int qi = t >> 15;
  const int code = 64 * W + 16 * (c & 3) + (l & 15);
  const int k    = 32 * (c >> 2) + 8 * (l >> 4);
  const float* src = emb + ((size_t)qi * KC + code) * DDIM + k;
  short8 v;
  #pragma unroll
  for (int j = 0; j < 8; ++j) v[j] = (short)f2bf(src[j]);
  *(short8*)(packE + (size_t)t * 8) = v;
}

__global__ __launch_bounds__(1024, 1)
void rvq_kernel(const float* __restrict__ x, const float* __restrict__ emb,
                const char* __restrict__ packEb, const float* __restrict__ e2g,
                float* __restrict__ out, float* __restrict__ outIdx,
                float* __restrict__ lossPart)
{
  __shared__ __align__(16) u16  Rh[BR * 256];   // 16KB rh residual (swizzled)
  __shared__ __align__(16) float e2L[QST * KC]; // 32KB all-stage ||e||^2
  __shared__ u64   slotL[BR];                   // packed (d,idx) argmin slots
  __shared__ int   cntL[BR];
  __shared__ int   candL[BR][MCAP];             // 1.5KB
  __shared__ float rnormL[BR];
  __shared__ float red[16];

  const int tid = threadIdx.x;
  const int w = tid >> 6, l = tid & 63;
  const int g = l >> 4, rb16 = l & 15;
  const int row = tid >> 5, sub = tid & 31;     // 32 rows x 32 threads
  const size_t rowBase = (size_t)blockIdx.x * BR;
  char* RhB = (char*)Rh;
  float lossAcc = 0.f;
  float r[8];                                   // f32 residual, d = 8*sub + i

  // ---- preload all e2 (32KB) ----
  *(f32x4*)&e2L[4 * tid]        = *(const f32x4*)&e2g[4 * tid];
  *(f32x4*)&e2L[4 * tid + 4096] = *(const f32x4*)&e2g[4 * tid + 4096];

  // ---- init: r = x slice; write rh to LDS; rnorm; reset slots ----
  {
    const float* xp = x + (rowBase + row) * DDIM + 8 * sub;
    f32x4 a = *(const f32x4*)(xp);
    f32x4 b = *(const f32x4*)(xp + 4);
    r[0]=a.x; r[1]=a.y; r[2]=a.z; r[3]=a.w;
    r[4]=b.x; r[5]=b.y; r[6]=b.z; r[7]=b.w;
    float rn = a.x*a.x + a.y*a.y + a.z*a.z + a.w*a.w
             + b.x*b.x + b.y*b.y + b.z*b.z + b.w*b.w;
    uint4 h;
    h.x = cvt_pk_bf16(r[0], r[1]); h.y = cvt_pk_bf16(r[2], r[3]);
    h.z = cvt_pk_bf16(r[4], r[5]); h.w = cvt_pk_bf16(r[6], r[7]);
    *(uint4*)(RhB + runit(row, sub)) = h;
    rn += __shfl_xor(rn, 1); rn += __shfl_xor(rn, 2); rn += __shfl_xor(rn, 4);
    rn += __shfl_xor(rn, 8); rn += __shfl_xor(rn, 16);
    if (sub == 0) rnormL[row] = rn;
    if (tid < BR) { slotL[tid] = ~0ULL; cntL[tid] = 0; }
  }
  __syncthreads();

  for (int qi = 0; qi < QST; ++qi) {
    const float* e2q = &e2L[qi * KC];

    // ---- GEMM: wave w covers codes [64w,64w+64) x 32 rows, K=256 ----
    f32x4 acc[4][2];
    #pragma unroll
    for (int a = 0; a < 4; ++a) {
      acc[a][0] = (f32x4){0.f, 0.f, 0.f, 0.f};
      acc[a][1] = (f32x4){0.f, 0.f, 0.f, 0.f};
    }
    const char* src = packEb + ((size_t)(qi * 16 + w) << 15) + (size_t)l * 16;
    #pragma unroll
    for (int ekt = 0; ekt < 8; ++ekt) {
      short8 Bf0 = *(const short8*)(RhB + runit(rb16,      ekt * 4 + g));
      short8 Bf1 = *(const short8*)(RhB + runit(16 + rb16, ekt * 4 + g));
      #pragma unroll
      for (int ci = 0; ci < 4; ++ci) {
        const short8 Af = *(const short8*)(src + ((ekt * 4 + ci) << 10));
        acc[ci][0] = __builtin_amdgcn_mfma_f32_16x16x32_bf16(Af, Bf0, acc[ci][0], 0, 0, 0);
        acc[ci][1] = __builtin_amdgcn_mfma_f32_16x16x32_bf16(Af, Bf1, acc[ci][1], 0, 0, 0);
      }
    }

    // ---- scoring: per-thread lex-min, wave combine, packed atomicMin ----
    {
      float bv0 = 3.4e38f, bv1 = 3.4e38f; int bi0 = 0, bi1 = 0;
      #pragma unroll
      for (int ci = 0; ci < 4; ++ci) {
        const int cb = 64 * w + 16 * ci + 4 * g;
        f32x4 e4 = *(const f32x4*)&e2q[cb];
        #pragma unroll
        for (int jj = 0; jj < 4; ++jj) {
          float d0 = fmaf(-2.f, acc[ci][0][jj], e4[jj]);
          float d1 = fmaf(-2.f, acc[ci][1][jj], e4[jj]);
          if (d0 < bv0) { bv0 = d0; bi0 = cb + jj; }
          if (d1 < bv1) { bv1 = d1; bi1 = cb + jj; }
        }
      }
      #pragma unroll
      for (int m = 16; m <= 32; m <<= 1) {
        float ov0 = __shfl_xor(bv0, m); int oi0 = __shfl_xor(bi0, m);
        float ov1 = __shfl_xor(bv1, m); int oi1 = __shfl_xor(bi1, m);
        if (ov0 < bv0 || (ov0 == bv0 && oi0 < bi0)) { bv0 = ov0; bi0 = oi0; }
        if (ov1 < bv1 || (ov1 == bv1 && oi1 < bi1)) { bv1 = ov1; bi1 = oi1; }
      }
      if (l < 16) {
        atomicMin(&slotL[l],      pkey(bv0, bi0));
        atomicMin(&slotL[16 + l], pkey(bv1, bi1));
      }
    }
    __syncthreads();   // slots final

    // ---- candidates within guaranteed margin ----
    {
      const float d00 = unfkey((u32)(slotL[rb16] >> 32));
      const float d01 = unfkey((u32)(slotL[16 + rb16] >> 32));
      const float thr0 = d00 + 0.36f * sqrtf(rnormL[rb16])      + 0.05f;
      const float thr1 = d01 + 0.36f * sqrtf(rnormL[16 + rb16]) + 0.05f;
      #pragma unroll
      for (int ci = 0; ci < 4; ++ci) {
        const int cb = 64 * w + 16 * ci + 4 * g;
        f32x4 e4 = *(const f32x4*)&e2q[cb];
        #pragma unroll
        for (int jj = 0; jj < 4; ++jj) {
          float d0 = fmaf(-2.f, acc[ci][0][jj], e4[jj]);
          float d1 = fmaf(-2.f, acc[ci][1][jj], e4[jj]);
          if (d0 <= thr0) {
            int p = atomicAdd(&cntL[rb16], 1);
            if (p < MCAP) candL[rb16][p] = cb + jj;
          }
          if (d1 <= thr1) {
            int p = atomicAdd(&cntL[16 + rb16], 1);
            if (p < MCAP) candL[16 + rb16][p] = cb + jj;
          }
        }
      }
    }
    __syncthreads();   // cnt/cand final

    // ---- fused resolve + exact rescue + update (32 thr/row, wave-internal) ----
    {
      const int cnt = cntL[row];
      int myidx;
      if (cnt == 1) {
        myidx = (int)(u32)(slotL[row] & 0xFFFFFFFFu);
      } else {
        float bd = 3.4e38f; int bi = 0x7fffffff;
        const int n = (cnt <= MCAP) ? cnt : KC;    // overflow -> full exact scan
        for (int k2 = 0; k2 < n; ++k2) {
          const int c = (cnt <= MCAP) ? candL[row][k2] : k2;
          const float* ep = emb + ((size_t)qi * KC + c) * DDIM + 8 * sub;
          f32x4 e0 = *(const f32x4*)(ep);
          f32x4 e1 = *(const f32x4*)(ep + 4);
          float dot = r[0]*e0.x + r[1]*e0.y + r[2]*e0.z + r[3]*e0.w
                    + r[4]*e1.x + r[5]*e1.y + r[6]*e1.z + r[7]*e1.w;
          dot += __shfl_xor(dot, 1); dot += __shfl_xor(dot, 2);
          dot += __shfl_xor(dot, 4); dot += __shfl_xor(dot, 8);
          dot += __shfl_xor(dot, 16);
          float d = e2q[c] - 2.f * dot;
          if (d < bd || (d == bd && c < bi)) { bd = d; bi = c; }
        }
        myidx = bi;   // uniform across the row group (shfl-reduced dot)
      }
      // update residual + loss + rh rewrite
      const float* ep = emb + ((size_t)qi * KC + myidx) * DDIM + 8 * sub;
      f32x4 e0 = *(const f32x4*)(ep);
      f32x4 e1 = *(const f32x4*)(ep + 4);
      float ls = 0.f;
      r[0] -= e0.x; ls += r[0]*r[0]; r[1] -= e0.y; ls += r[1]*r[1];
      r[2] -= e0.z; ls += r[2]*r[2]; r[3] -= e0.w; ls += r[3]*r[3];
      r[4] -= e1.x; ls += r[4]*r[4]; r[5] -= e1.y; ls += r[5]*r[5];
      r[6] -= e1.z; ls += r[6]*r[6]; r[7] -= e1.w; ls += r[7]*r[7];
      uint4 h;
      h.x = cvt_pk_bf16(r[0], r[1]); h.y = cvt_pk_bf16(r[2], r[3]);
      h.z = cvt_pk_bf16(r[4], r[5]); h.w = cvt_pk_bf16(r[6], r[7]);
      *(uint4*)(RhB + runit(row, sub)) = h;
      lossAcc += ls;
      float rn = ls;
      rn += __shfl_xor(rn, 1); rn += __shfl_xor(rn, 2); rn += __shfl_xor(rn, 4);
      rn += __shfl_xor(rn, 8); rn += __shfl_xor(rn, 16);
      if (sub == 0) {
        rnormL[row] = rn;
        outIdx[(rowBase + row) * QST + qi] = (float)myidx;
        slotL[row] = ~0ULL;        // reset for next stage (post-read, pre-barrier)
        cntL[row] = 0;
      }
    }
    __syncthreads();   // Rh/rnorm/resets visible before next GEMM+scoring
  }

  // ---- final: out = x - r_final ----
  {
    const float* xp = x + (rowBase + row) * DDIM + 8 * sub;
    float* op = out + (rowBase + row) * DDIM + 8 * sub;
    f32x4 xa = *(const f32x4*)(xp);
    f32x4 xb = *(const f32x4*)(xp + 4);
    f32x4 oa, ob;
    oa.x = xa.x - r[0]; oa.y = xa.y - r[1]; oa.z = xa.z - r[2]; oa.w = xa.w - r[3];
    ob.x = xb.x - r[4]; ob.y = xb.y - r[5]; ob.z = xb.z - r[6]; ob.w = xb.w - r[7];
    *(f32x4*)(op)     = oa;
    *(f32x4*)(op + 4) = ob;
  }

  // ---- deterministic per-block loss partial ----
  {
    float s = lossAcc;
    #pragma unroll
    for (int m = 32; m >= 1; m >>= 1) s += __shfl_xor(s, m);
    if (l == 0) red[w] = s;
    __syncthreads();
    if (tid == 0) {
      float t2 = 0.f;
      #pragma unroll
      for (int wv = 0; wv < 16; ++wv) t2 += red[wv];
      lossPart[blockIdx.x] = t2;
    }
  }
}

__global__ void loss_final(const float* __restrict__ part, float* __restrict__ outLoss) {
  __shared__ float buf[256];
  const int t = threadIdx.x;
  float s = 0.f;
  #pragma unroll
  for (int k = 0; k < 8; ++k) s += part[t + 256 * k];
  buf[t] = s;
  __syncthreads();
  for (int st = 128; st >= 1; st >>= 1) {
    if (t < st) buf[t] += buf[t + st];
    __syncthreads();
  }
  if (t == 0) *outLoss = buf[0] * (1.25f / 16777216.f);
}

extern "C" void kernel_launch(void* const* d_in, const int* in_sizes, int n_in,
                              void* d_out, int out_size, void* d_ws, size_t ws_size,
                              hipStream_t stream) {
  (void)in_sizes; (void)n_in; (void)out_size; (void)ws_size;
  const float* x   = (const float*)d_in[0];
  const float* emb = (const float*)d_in[1];
  float* out     = (float*)d_out;
  float* outLoss = out + (size_t)NROWS * DDIM;            // 16777216
  float* outIdx  = outLoss + 1;                           // indices as float
  char*  packE   = (char*)d_ws;                           // 4 MB bf16 A-frag stream
  float* e2      = (float*)(packE + (size_t)QST * 16 * 32 * 1024);  // 8192 f32
  float* part    = e2 + QST * KC;                         // 2048 f32

  pack_kernel<<<dim3(1024), dim3(256), 0, stream>>>(emb, (u16*)packE);
  e2_kernel<<<dim3(QST * KC / 4), dim3(256), 0, stream>>>(emb, e2);
  rvq_kernel<<<dim3(NROWS / BR), dim3(1024), 0, stream>>>(x, emb, packE, e2, out, outIdx, part);
  loss_final<<<dim3(1), dim3(256), 0, stream>>>(part, outLoss);
}